// Round 4
// baseline (102.712 us; speedup 1.0000x reference)
//
#include <hip/hip_runtime.h>

#define DEV static __device__ __forceinline__

// ---- lane-exchange primitives ----
template <int CTRL>
DEV float dpp_xor(float v) {
    int i = __float_as_int(v);
    i = __builtin_amdgcn_update_dpp(i, i, CTRL, 0xF, 0xF, false);
    return __int_as_float(i);
}
template <int PAT>
DEV float swz(float v) {
    return __int_as_float(__builtin_amdgcn_ds_swizzle(__float_as_int(v), PAT));
}
DEV float bperm(int byteaddr, float v) {
    return __int_as_float(__builtin_amdgcn_ds_bpermute(byteaddr, __float_as_int(v)));
}

// xor-exchange: masks 1,2,8 on VALU (DPP); 4,16 via ds_swizzle; 32 via bpermute(a32)
template <int MASK>
DEV float lanexor(float v, int a32) {
    if constexpr (MASK == 1)       return dpp_xor<0xB1>(v);   // quad_perm [1,0,3,2]
    else if constexpr (MASK == 2)  return dpp_xor<0x4E>(v);   // quad_perm [2,3,0,1]
    else if constexpr (MASK == 8)  return dpp_xor<0x128>(v);  // row_ror:8 == xor 8
    else if constexpr (MASK == 4)  return swz<0x101F>(v);     // BitMode xor=4
    else if constexpr (MASK == 16) return swz<0x401F>(v);     // BitMode xor=16
    else                           return bperm(a32, v);      // xor 32
}
template <int MASK>
DEV float2 lanexor2(float2 v, int a32) {
    return make_float2(lanexor<MASK>(v.x, a32), lanexor<MASK>(v.y, a32));
}

DEV float wave_sum(float v, int a32) {
    v += lanexor<1>(v, 0);
    v += lanexor<2>(v, 0);
    v += lanexor<4>(v, 0);
    v += lanexor<8>(v, 0);
    v += lanexor<16>(v, 0);
    v += bperm(a32, v);
    return v;
}

DEV float2 cmul(float2 a, float2 b) {
    return make_float2(a.x * b.x - a.y * b.y, a.x * b.y + a.y * b.x);
}

// Qubit q <-> bit P = 9-q of state index s = lane*16 + r.
// Lane bits 5..0 = state bits 9..4; reg bits 3..0 = state bits 3..0.
// State: float2 st[16], .x = re, .y = im. Two states A,B per wave.

template <int P>
DEV void ry2(float2 (&A)[16], float2 (&B)[16], float c, float s, int lane, int a32) {
    if constexpr (P >= 4) {
        constexpr int mask = 1 << (P - 4);
        const float sg = (lane & mask) ? s : -s;
#pragma unroll
        for (int r = 0; r < 16; ++r) {
            float2 pa = lanexor2<mask>(A[r], a32);
            float2 pb = lanexor2<mask>(B[r], a32);
            A[r].x = fmaf(c, A[r].x, sg * pa.x);
            A[r].y = fmaf(c, A[r].y, sg * pa.y);
            B[r].x = fmaf(c, B[r].x, sg * pb.x);
            B[r].y = fmaf(c, B[r].y, sg * pb.y);
        }
    } else {
        constexpr int tb = 1 << P;
#pragma unroll
        for (int r = 0; r < 16; ++r) {
            if (!(r & tb)) {
                const int r2 = r | tb;
                float2 a0 = A[r], a1 = A[r2];
                A[r]  = make_float2(fmaf(c, a0.x, -s * a1.x), fmaf(c, a0.y, -s * a1.y));
                A[r2] = make_float2(fmaf(s, a0.x,  c * a1.x), fmaf(s, a0.y,  c * a1.y));
                float2 b0 = B[r], b1 = B[r2];
                B[r]  = make_float2(fmaf(c, b0.x, -s * b1.x), fmaf(c, b0.y, -s * b1.y));
                B[r2] = make_float2(fmaf(s, b0.x,  c * b1.x), fmaf(s, b0.y,  c * b1.y));
            }
        }
    }
}

// Composed lane map of CNOT chain C(q0->q1)..C(q4->q5).
DEV int g_of(int a) {
    a ^= ((a >> 1) & 1) ? 1 : 0;   // C(q4->q5)
    a ^= ((a >> 2) & 1) ? 2 : 0;   // C(q3->q4)
    a ^= ((a >> 3) & 1) ? 4 : 0;   // C(q2->q3)
    a ^= ((a >> 4) & 1) ? 8 : 0;   // C(q1->q2)
    a ^= ((a >> 5) & 1) ? 16 : 0;  // C(q0->q1)
    return a;
}

// Precompute cos/sin of weight angles (batch-independent) into workspace.
__global__ void dqc_trig_kernel(const float* __restrict__ w_ry,
                                const float* __restrict__ w_rz,
                                float2* __restrict__ trig) {
    int t = threadIdx.x;  // 0..79
    if (t < 80) {
        float ang = (t < 40 ? w_ry[t] : w_rz[t - 40]) * 0.5f;
        trig[t] = make_float2(__cosf(ang), __sinf(ang));
    }
}

__global__ __launch_bounds__(256, 2) void dqc_main_kernel(
    const float* __restrict__ x, const float* __restrict__ pre_w,
    const float* __restrict__ pre_b, const float* __restrict__ post_w,
    const float* __restrict__ post_b, const float2* __restrict__ trig,
    float* __restrict__ out, int B) {
    const int lane = threadIdx.x & 63;
    const int wid = threadIdx.x >> 6;
    const int w = blockIdx.x * 4 + wid;
    const int b0 = w * 2, b1 = w * 2 + 1;
    if (b0 >= B) return;
    const int b1c = (b1 < B) ? b1 : b0;  // safe load addr for odd tail

    // precomputed exchange addresses (bytes)
    const int a32 = (lane ^ 32) << 2;
    // Composed CNOT: C(q9->q0) conjugated through reg-CNOTs = flip lane bit5
    // iff (lane&1) ^ parity(r&15), composed with g_of. addr depends on reg parity.
    const int h0 = lane ^ ((lane & 1) ? 32 : 0);
    const int cA = g_of(h0) << 2;
    const int cB = g_of(h0 ^ 32) << 2;

    // ---- q_in for both elements: float4-vectorized dot products ----
    float thA[10], thB[10];
#pragma unroll
    for (int i = 0; i < 10; ++i) { thA[i] = 0.f; thB[i] = 0.f; }
    const float4* xa4 = (const float4*)(x + (size_t)b0 * 512);
    const float4* xb4 = (const float4*)(x + (size_t)b1c * 512);
#pragma unroll
    for (int k = 0; k < 2; ++k) {
        const int vi = lane + 64 * k;  // float4 index within row (0..127)
        float4 xva = xa4[vi];
        float4 xvb = xb4[vi];
#pragma unroll
        for (int i = 0; i < 10; ++i) {
            float4 wv = ((const float4*)(pre_w + i * 512))[vi];
            thA[i] = fmaf(xva.x, wv.x, thA[i]);
            thB[i] = fmaf(xvb.x, wv.x, thB[i]);
            thA[i] = fmaf(xva.y, wv.y, thA[i]);
            thB[i] = fmaf(xvb.y, wv.y, thB[i]);
            thA[i] = fmaf(xva.z, wv.z, thA[i]);
            thB[i] = fmaf(xvb.z, wv.z, thB[i]);
            thA[i] = fmaf(xva.w, wv.w, thA[i]);
            thB[i] = fmaf(xvb.w, wv.w, thB[i]);
        }
    }
#pragma unroll
    for (int i = 0; i < 10; ++i) {
        thA[i] = wave_sum(thA[i], a32) + pre_b[i];
        thB[i] = wave_sum(thB[i], a32) + pre_b[i];
    }

    // ---- product state after 10 initial RYs on |0..0>: purely real ----
    float2 A[16], Bst[16];
    {
        float ccA[10], ssA[10], ccB[10], ssB[10];
#pragma unroll
        for (int i = 0; i < 10; ++i) {
            float aa = thA[i] * 0.5f, ab = thB[i] * 0.5f;
            ccA[i] = __cosf(aa); ssA[i] = __sinf(aa);
            ccB[i] = __cosf(ab); ssB[i] = __sinf(ab);
        }
        float lpA = 1.f, lpB = 1.f;
#pragma unroll
        for (int i = 0; i < 6; ++i) {  // qubit i <-> lane bit 5-i
            const int bit = (lane >> (5 - i)) & 1;
            lpA *= bit ? ssA[i] : ccA[i];
            lpB *= bit ? ssB[i] : ccB[i];
        }
        float hiA[4], loA[4], hiB[4], loB[4];
#pragma unroll
        for (int j = 0; j < 4; ++j) {
            hiA[j] = lpA * ((j >> 1) ? ssA[6] : ccA[6]) * ((j & 1) ? ssA[7] : ccA[7]);
            loA[j] = ((j >> 1) ? ssA[8] : ccA[8]) * ((j & 1) ? ssA[9] : ccA[9]);
            hiB[j] = lpB * ((j >> 1) ? ssB[6] : ccB[6]) * ((j & 1) ? ssB[7] : ccB[7]);
            loB[j] = ((j >> 1) ? ssB[8] : ccB[8]) * ((j & 1) ? ssB[9] : ccB[9]);
        }
#pragma unroll
        for (int r = 0; r < 16; ++r) {
            A[r]   = make_float2(hiA[r >> 2] * loA[r & 3], 0.f);
            Bst[r] = make_float2(hiB[r >> 2] * loB[r & 3], 0.f);
        }
    }

    // ---- variational layers ----
#pragma unroll 1
    for (int l = 0; l < 4; ++l) {
        const float2* tr = trig + l * 10;       // RY(layer, qubit)
        const float2* tz = trig + 40 + l * 10;  // RZ(layer, qubit)

        // All 10 RYs (RZs deferred past the RY block; RZ(q) commutes with RY(q'!=q))
        ry2<9>(A, Bst, tr[0].x, tr[0].y, lane, a32);
        ry2<8>(A, Bst, tr[1].x, tr[1].y, lane, a32);
        ry2<7>(A, Bst, tr[2].x, tr[2].y, lane, a32);
        ry2<6>(A, Bst, tr[3].x, tr[3].y, lane, a32);
        ry2<5>(A, Bst, tr[4].x, tr[4].y, lane, a32);
        ry2<4>(A, Bst, tr[5].x, tr[5].y, lane, a32);
        ry2<3>(A, Bst, tr[6].x, tr[6].y, lane, a32);
        ry2<2>(A, Bst, tr[7].x, tr[7].y, lane, a32);
        ry2<1>(A, Bst, tr[8].x, tr[8].y, lane, a32);
        ry2<0>(A, Bst, tr[9].x, tr[9].y, lane, a32);

        // Combined diagonal phase for all 10 RZs (shared between A and B).
        // bit=0 scales by (c,-s); bit=1 by (c,+s).
        float2 pl;  // lane-dependent phase from qubits 0..5
        {
            float2 z0 = tz[0];
            pl = make_float2(z0.x, ((lane >> 5) & 1) ? z0.y : -z0.y);
#pragma unroll
            for (int q = 1; q < 6; ++q) {
                float2 z = tz[q];
                float sq = ((lane >> (5 - q)) & 1) ? z.y : -z.y;
                pl = cmul(pl, make_float2(z.x, sq));
            }
        }
        float2 p67[4], p89[4];
        {
            const float c6 = tz[6].x, s6 = tz[6].y, c7 = tz[7].x, s7 = tz[7].y;
            const float c8 = tz[8].x, s8 = tz[8].y, c9 = tz[9].x, s9 = tz[9].y;
#pragma unroll
            for (int j = 0; j < 4; ++j) {
                float sg6 = (j >> 1) ? s6 : -s6;  // qubit6 <-> reg bit 3
                float sg7 = (j & 1) ? s7 : -s7;   // qubit7 <-> reg bit 2
                p67[j] = cmul(cmul(make_float2(c6, sg6), make_float2(c7, sg7)), pl);
                float sg8 = (j >> 1) ? s8 : -s8;  // qubit8 <-> reg bit 1
                float sg9 = (j & 1) ? s9 : -s9;   // qubit9 <-> reg bit 0
                p89[j] = cmul(make_float2(c8, sg8), make_float2(c9, sg9));
            }
        }
#pragma unroll
        for (int r = 0; r < 16; ++r) {
            const int j = r >> 2, k = r & 3;
            A[r]   = cmul(cmul(A[r], p67[j]), p89[k]);
            Bst[r] = cmul(cmul(Bst[r], p67[j]), p89[k]);
        }

        // CNOT ring:
        // (1) composed lane permutation: C(q0->q1)..C(q4->q5) + conjugated C(q9->q0)
#pragma unroll
        for (int r = 0; r < 16; ++r) {
            const int addr = ((0x6996 >> r) & 1) ? cB : cA;  // parity of r&15
            A[r].x = bperm(addr, A[r].x);
            A[r].y = bperm(addr, A[r].y);
            Bst[r].x = bperm(addr, Bst[r].x);
            Bst[r].y = bperm(addr, Bst[r].y);
        }
        // (2) C(q5->q6): lane bit0 control, reg bit3 target
        {
            const bool ctrl = (lane & 1) != 0;
#pragma unroll
            for (int r = 0; r < 8; ++r) {
                const int r2 = r | 8;
                float2 t0 = A[r], t1 = A[r2];
                A[r]  = ctrl ? t1 : t0;
                A[r2] = ctrl ? t0 : t1;
                float2 u0 = Bst[r], u1 = Bst[r2];
                Bst[r]  = ctrl ? u1 : u0;
                Bst[r2] = ctrl ? u0 : u1;
            }
        }
        // (3) register renames: C(q6->q7), C(q7->q8), C(q8->q9)
#pragma unroll
        for (int r = 0; r < 16; ++r)
            if ((r & 8) && !(r & 4)) {
                const int r2 = r | 4;
                float2 t = A[r]; A[r] = A[r2]; A[r2] = t;
                t = Bst[r]; Bst[r] = Bst[r2]; Bst[r2] = t;
            }
#pragma unroll
        for (int r = 0; r < 16; ++r)
            if ((r & 4) && !(r & 2)) {
                const int r2 = r | 2;
                float2 t = A[r]; A[r] = A[r2]; A[r2] = t;
                t = Bst[r]; Bst[r] = Bst[r2]; Bst[r2] = t;
            }
#pragma unroll
        for (int r = 0; r < 16; ++r)
            if ((r & 2) && !(r & 1)) {
                const int r2 = r | 1;
                float2 t = A[r]; A[r] = A[r2]; A[r2] = t;
                t = Bst[r]; Bst[r] = Bst[r2]; Bst[r2] = t;
            }
    }

    // ---- out[b] = sum_s |psi_s|^2 * sum_j post_w[j]*(1-2*bit_j(s)) + post_b ----
    float laneC = 0.f;
#pragma unroll
    for (int j = 0; j < 6; ++j) {
        int bit = (lane >> (5 - j)) & 1;
        laneC += post_w[j] * (1.f - 2.f * (float)bit);
    }
    float accA = 0.f, accB = 0.f;
#pragma unroll
    for (int r = 0; r < 16; ++r) {
        float regC = 0.f;
#pragma unroll
        for (int j = 6; j < 10; ++j) {
            int bit = (r >> (9 - j)) & 1;
            regC += post_w[j] * (1.f - 2.f * (float)bit);
        }
        const float coef = laneC + regC;
        accA = fmaf(fmaf(A[r].x, A[r].x, A[r].y * A[r].y), coef, accA);
        accB = fmaf(fmaf(Bst[r].x, Bst[r].x, Bst[r].y * Bst[r].y), coef, accB);
    }
    accA = wave_sum(accA, a32);
    accB = wave_sum(accB, a32);
    if (lane == 0) {
        out[b0] = accA + post_b[0];
        if (b1 < B) out[b1] = accB + post_b[0];
    }
}

extern "C" void kernel_launch(void* const* d_in, const int* in_sizes, int n_in,
                              void* d_out, int out_size, void* d_ws, size_t ws_size,
                              hipStream_t stream) {
    const float* x      = (const float*)d_in[0];
    const float* pre_w  = (const float*)d_in[1];
    const float* pre_b  = (const float*)d_in[2];
    const float* post_w = (const float*)d_in[3];
    const float* post_b = (const float*)d_in[4];
    const float* w_ry   = (const float*)d_in[5];
    const float* w_rz   = (const float*)d_in[6];
    float* out = (float*)d_out;
    float2* trig = (float2*)d_ws;

    const int B = in_sizes[0] / 512;  // 4096

    dqc_trig_kernel<<<1, 128, 0, stream>>>(w_ry, w_rz, trig);
    const int blocks = (B + 7) / 8;  // 4 waves/block, 2 elements/wave
    dqc_main_kernel<<<blocks, 256, 0, stream>>>(x, pre_w, pre_b, post_w,
                                                post_b, trig, out, B);
}

// Round 5
// 101.165 us; speedup vs baseline: 1.0153x; 1.0153x over previous
//
#include <hip/hip_runtime.h>

#define DEV static __device__ __forceinline__

typedef float f2 __attribute__((ext_vector_type(2)));

// ---- lane-exchange primitives ----
template <int CTRL>
DEV float dpp_xor(float v) {
    int i = __float_as_int(v);
    i = __builtin_amdgcn_update_dpp(i, i, CTRL, 0xF, 0xF, false);
    return __int_as_float(i);
}
template <int PAT>
DEV float swz(float v) {
    return __int_as_float(__builtin_amdgcn_ds_swizzle(__float_as_int(v), PAT));
}
DEV float bperm(int byteaddr, float v) {
    return __int_as_float(__builtin_amdgcn_ds_bpermute(byteaddr, __float_as_int(v)));
}

// xor-exchange: masks 1,2,8 on VALU (DPP); 4,16 via ds_swizzle; 32 via bpermute(a32)
template <int MASK>
DEV float lanexor(float v, int a32) {
    if constexpr (MASK == 1)       return dpp_xor<0xB1>(v);   // quad_perm [1,0,3,2]
    else if constexpr (MASK == 2)  return dpp_xor<0x4E>(v);   // quad_perm [2,3,0,1]
    else if constexpr (MASK == 8)  return dpp_xor<0x128>(v);  // row_ror:8 == xor 8
    else if constexpr (MASK == 4)  return swz<0x101F>(v);     // BitMode xor=4
    else if constexpr (MASK == 16) return swz<0x401F>(v);     // BitMode xor=16
    else                           return bperm(a32, v);      // xor 32
}
template <int MASK>
DEV f2 lanexor2(f2 v, int a32) {
    f2 r;
    r.x = lanexor<MASK>(v.x, a32);
    r.y = lanexor<MASK>(v.y, a32);
    return r;
}

DEV float wave_sum(float v, int a32) {
    v += lanexor<1>(v, 0);
    v += lanexor<2>(v, 0);
    v += lanexor<4>(v, 0);
    v += lanexor<8>(v, 0);
    v += lanexor<16>(v, 0);
    v += bperm(a32, v);
    return v;
}

// complex numbers as f2 {re, im}
DEV f2 cmulc(f2 a, f2 b) {  // full complex multiply (table build, shared work)
    f2 r;
    r.x = a.x * b.x - a.y * b.y;
    r.y = a.x * b.y + a.y * b.x;
    return r;
}
DEV f2 cmulf2(f2 a, f2 p) {  // state-amp * phase, packed-friendly form
    f2 sw;
    sw.x = -a.y;
    sw.y = a.x;
    return p.x * a + p.y * sw;  // pk_mul + pk_fma (+1 swap)
}

// Qubit q <-> bit P = 9-q of state index s = lane*16 + r.
// Lane bits 5..0 = state bits 9..4; reg bits 3..0 = state bits 3..0.
// State: f2 st[16] = (re, im). Two batch elements A,B per wave.

template <int P>
DEV void ry2(f2 (&A)[16], f2 (&B)[16], float c, float s, int lane, int a32) {
    if constexpr (P >= 4) {
        constexpr int mask = 1 << (P - 4);
        const float sg = (lane & mask) ? s : -s;
#pragma unroll
        for (int r = 0; r < 16; ++r) {
            f2 pa = lanexor2<mask>(A[r], a32);
            f2 pb = lanexor2<mask>(B[r], a32);
            A[r] = c * A[r] + sg * pa;  // v_pk_fma_f32
            B[r] = c * B[r] + sg * pb;
        }
    } else {
        constexpr int tb = 1 << P;
#pragma unroll
        for (int r = 0; r < 16; ++r) {
            if (!(r & tb)) {
                const int r2 = r | tb;
                f2 a0 = A[r], a1 = A[r2];
                A[r]  = c * a0 - s * a1;
                A[r2] = s * a0 + c * a1;
                f2 b0 = B[r], b1 = B[r2];
                B[r]  = c * b0 - s * b1;
                B[r2] = s * b0 + c * b1;
            }
        }
    }
}

// Composed lane map of CNOT chain C(q0->q1)..C(q4->q5).
DEV int g_of(int a) {
    a ^= ((a >> 1) & 1) ? 1 : 0;   // C(q4->q5)
    a ^= ((a >> 2) & 1) ? 2 : 0;   // C(q3->q4)
    a ^= ((a >> 3) & 1) ? 4 : 0;   // C(q2->q3)
    a ^= ((a >> 4) & 1) ? 8 : 0;   // C(q1->q2)
    a ^= ((a >> 5) & 1) ? 16 : 0;  // C(q0->q1)
    return a;
}

__global__ __launch_bounds__(256, 2) void dqc_main_kernel(
    const float* __restrict__ x, const float* __restrict__ pre_w,
    const float* __restrict__ pre_b, const float* __restrict__ post_w,
    const float* __restrict__ post_b, const float* __restrict__ w_ry,
    const float* __restrict__ w_rz, float* __restrict__ out, int B) {
    const int lane = threadIdx.x & 63;
    const int wid = threadIdx.x >> 6;
    const int w = blockIdx.x * 4 + wid;

    // ---- per-block trig table (replaces the separate trig kernel) ----
    __shared__ f2 tt[80];  // [0..39]=RY(l,q) half-angle (c,s); [40..79]=RZ
    {
        const int t = threadIdx.x;
        if (t < 80) {
            float ang = (t < 40 ? w_ry[t] : w_rz[t - 40]) * 0.5f;
            f2 z;
            z.x = __cosf(ang);
            z.y = __sinf(ang);
            tt[t] = z;
        }
    }
    __syncthreads();

    const int b0 = w * 2, b1 = w * 2 + 1;
    const int b0c = (b0 < B) ? b0 : B - 1;
    const int b1c = (b1 < B) ? b1 : B - 1;

    // precomputed exchange addresses (bytes)
    const int a32 = (lane ^ 32) << 2;
    // Composed CNOT: C(q9->q0) conjugated through reg-CNOTs = flip lane bit5
    // iff (lane&1) ^ parity(r&15), composed with g_of. addr depends on reg parity.
    const int h0 = lane ^ ((lane & 1) ? 32 : 0);
    const int cA = g_of(h0) << 2;
    const int cB = g_of(h0 ^ 32) << 2;

    // ---- q_in for both elements: float4-vectorized dot products ----
    float thA[10], thB[10];
#pragma unroll
    for (int i = 0; i < 10; ++i) { thA[i] = 0.f; thB[i] = 0.f; }
    const float4* xa4 = (const float4*)(x + (size_t)b0c * 512);
    const float4* xb4 = (const float4*)(x + (size_t)b1c * 512);
#pragma unroll
    for (int k = 0; k < 2; ++k) {
        const int vi = lane + 64 * k;
        float4 xva = xa4[vi];
        float4 xvb = xb4[vi];
#pragma unroll
        for (int i = 0; i < 10; ++i) {
            float4 wv = ((const float4*)(pre_w + i * 512))[vi];
            thA[i] = fmaf(xva.x, wv.x, thA[i]);
            thB[i] = fmaf(xvb.x, wv.x, thB[i]);
            thA[i] = fmaf(xva.y, wv.y, thA[i]);
            thB[i] = fmaf(xvb.y, wv.y, thB[i]);
            thA[i] = fmaf(xva.z, wv.z, thA[i]);
            thB[i] = fmaf(xvb.z, wv.z, thB[i]);
            thA[i] = fmaf(xva.w, wv.w, thA[i]);
            thB[i] = fmaf(xvb.w, wv.w, thB[i]);
        }
    }
#pragma unroll
    for (int i = 0; i < 10; ++i) {
        thA[i] = wave_sum(thA[i], a32) + pre_b[i];
        thB[i] = wave_sum(thB[i], a32) + pre_b[i];
    }

    // ---- product state after 10 initial RYs on |0..0>: purely real ----
    f2 A[16], Bs[16];
    {
        float ccA[10], ssA[10], ccB[10], ssB[10];
#pragma unroll
        for (int i = 0; i < 10; ++i) {
            float aa = thA[i] * 0.5f, ab = thB[i] * 0.5f;
            ccA[i] = __cosf(aa); ssA[i] = __sinf(aa);
            ccB[i] = __cosf(ab); ssB[i] = __sinf(ab);
        }
        float lpA = 1.f, lpB = 1.f;
#pragma unroll
        for (int i = 0; i < 6; ++i) {  // qubit i <-> lane bit 5-i
            const int bit = (lane >> (5 - i)) & 1;
            lpA *= bit ? ssA[i] : ccA[i];
            lpB *= bit ? ssB[i] : ccB[i];
        }
        float hiA[4], loA[4], hiB[4], loB[4];
#pragma unroll
        for (int j = 0; j < 4; ++j) {
            hiA[j] = lpA * ((j >> 1) ? ssA[6] : ccA[6]) * ((j & 1) ? ssA[7] : ccA[7]);
            loA[j] = ((j >> 1) ? ssA[8] : ccA[8]) * ((j & 1) ? ssA[9] : ccA[9]);
            hiB[j] = lpB * ((j >> 1) ? ssB[6] : ccB[6]) * ((j & 1) ? ssB[7] : ccB[7]);
            loB[j] = ((j >> 1) ? ssB[8] : ccB[8]) * ((j & 1) ? ssB[9] : ccB[9]);
        }
#pragma unroll
        for (int r = 0; r < 16; ++r) {
            A[r].x = hiA[r >> 2] * loA[r & 3];
            A[r].y = 0.f;
            Bs[r].x = hiB[r >> 2] * loB[r & 3];
            Bs[r].y = 0.f;
        }
    }

    // ---- variational layers ----
#pragma unroll 1
    for (int l = 0; l < 4; ++l) {
        const int base = l * 10;

        // All 10 RYs (RZs deferred; RZ(q) commutes with RY(q'!=q))
        { f2 z = tt[base + 0]; ry2<9>(A, Bs, z.x, z.y, lane, a32); }
        { f2 z = tt[base + 1]; ry2<8>(A, Bs, z.x, z.y, lane, a32); }
        { f2 z = tt[base + 2]; ry2<7>(A, Bs, z.x, z.y, lane, a32); }
        { f2 z = tt[base + 3]; ry2<6>(A, Bs, z.x, z.y, lane, a32); }
        { f2 z = tt[base + 4]; ry2<5>(A, Bs, z.x, z.y, lane, a32); }
        { f2 z = tt[base + 5]; ry2<4>(A, Bs, z.x, z.y, lane, a32); }
        { f2 z = tt[base + 6]; ry2<3>(A, Bs, z.x, z.y, lane, a32); }
        { f2 z = tt[base + 7]; ry2<2>(A, Bs, z.x, z.y, lane, a32); }
        { f2 z = tt[base + 8]; ry2<1>(A, Bs, z.x, z.y, lane, a32); }
        { f2 z = tt[base + 9]; ry2<0>(A, Bs, z.x, z.y, lane, a32); }

        // Combined diagonal phase for all 10 RZs (shared between A and B).
        // bit=0 scales by (c,-s); bit=1 by (c,+s).
        f2 ptab[16];
        {
            f2 z0 = tt[40 + base + 0];
            f2 pl;
            pl.x = z0.x;
            pl.y = ((lane >> 5) & 1) ? z0.y : -z0.y;
#pragma unroll
            for (int q = 1; q < 6; ++q) {
                f2 z = tt[40 + base + q];
                f2 zz;
                zz.x = z.x;
                zz.y = ((lane >> (5 - q)) & 1) ? z.y : -z.y;
                pl = cmulc(pl, zz);
            }
            f2 z6 = tt[40 + base + 6], z7 = tt[40 + base + 7];
            f2 z8 = tt[40 + base + 8], z9 = tt[40 + base + 9];
            f2 p67[4], p89[4];
#pragma unroll
            for (int j = 0; j < 4; ++j) {
                f2 a6, a7, a8, a9;
                a6.x = z6.x; a6.y = (j >> 1) ? z6.y : -z6.y;  // qubit6 <-> reg bit 3
                a7.x = z7.x; a7.y = (j & 1) ? z7.y : -z7.y;   // qubit7 <-> reg bit 2
                p67[j] = cmulc(cmulc(a6, a7), pl);
                a8.x = z8.x; a8.y = (j >> 1) ? z8.y : -z8.y;  // qubit8 <-> reg bit 1
                a9.x = z9.x; a9.y = (j & 1) ? z9.y : -z9.y;   // qubit9 <-> reg bit 0
                p89[j] = cmulc(a8, a9);
            }
#pragma unroll
            for (int r = 0; r < 16; ++r) ptab[r] = cmulc(p67[r >> 2], p89[r & 3]);
        }
#pragma unroll
        for (int r = 0; r < 16; ++r) {
            A[r]  = cmulf2(A[r], ptab[r]);
            Bs[r] = cmulf2(Bs[r], ptab[r]);
        }

        // CNOT ring:
        // (1) composed lane permutation: C(q0->q1)..C(q4->q5) + conjugated C(q9->q0)
#pragma unroll
        for (int r = 0; r < 16; ++r) {
            const int addr = ((0x6996 >> r) & 1) ? cB : cA;  // parity of r&15
            A[r].x = bperm(addr, A[r].x);
            A[r].y = bperm(addr, A[r].y);
            Bs[r].x = bperm(addr, Bs[r].x);
            Bs[r].y = bperm(addr, Bs[r].y);
        }
        // (2) C(q5->q6): lane bit0 control, reg bit3 target
        {
            const bool ctrl = (lane & 1) != 0;
#pragma unroll
            for (int r = 0; r < 8; ++r) {
                const int r2 = r | 8;
                f2 t0 = A[r], t1 = A[r2];
                A[r]  = ctrl ? t1 : t0;
                A[r2] = ctrl ? t0 : t1;
                f2 u0 = Bs[r], u1 = Bs[r2];
                Bs[r]  = ctrl ? u1 : u0;
                Bs[r2] = ctrl ? u0 : u1;
            }
        }
        // (3) register renames: C(q6->q7), C(q7->q8), C(q8->q9)
#pragma unroll
        for (int r = 0; r < 16; ++r)
            if ((r & 8) && !(r & 4)) {
                const int r2 = r | 4;
                f2 t = A[r]; A[r] = A[r2]; A[r2] = t;
                t = Bs[r]; Bs[r] = Bs[r2]; Bs[r2] = t;
            }
#pragma unroll
        for (int r = 0; r < 16; ++r)
            if ((r & 4) && !(r & 2)) {
                const int r2 = r | 2;
                f2 t = A[r]; A[r] = A[r2]; A[r2] = t;
                t = Bs[r]; Bs[r] = Bs[r2]; Bs[r2] = t;
            }
#pragma unroll
        for (int r = 0; r < 16; ++r)
            if ((r & 2) && !(r & 1)) {
                const int r2 = r | 1;
                f2 t = A[r]; A[r] = A[r2]; A[r2] = t;
                t = Bs[r]; Bs[r] = Bs[r2]; Bs[r2] = t;
            }
    }

    // ---- out[b] = sum_s |psi_s|^2 * sum_j post_w[j]*(1-2*bit_j(s)) + post_b ----
    float laneC = 0.f;
#pragma unroll
    for (int j = 0; j < 6; ++j) {
        int bit = (lane >> (5 - j)) & 1;
        laneC += post_w[j] * (1.f - 2.f * (float)bit);
    }
    float accA = 0.f, accB = 0.f;
#pragma unroll
    for (int r = 0; r < 16; ++r) {
        float regC = 0.f;
#pragma unroll
        for (int j = 6; j < 10; ++j) {
            int bit = (r >> (9 - j)) & 1;
            regC += post_w[j] * (1.f - 2.f * (float)bit);
        }
        const float coef = laneC + regC;
        accA = fmaf(fmaf(A[r].x, A[r].x, A[r].y * A[r].y), coef, accA);
        accB = fmaf(fmaf(Bs[r].x, Bs[r].x, Bs[r].y * Bs[r].y), coef, accB);
    }
    accA = wave_sum(accA, a32);
    accB = wave_sum(accB, a32);
    if (lane == 0) {
        if (b0 < B) out[b0] = accA + post_b[0];
        if (b1 < B) out[b1] = accB + post_b[0];
    }
}

extern "C" void kernel_launch(void* const* d_in, const int* in_sizes, int n_in,
                              void* d_out, int out_size, void* d_ws, size_t ws_size,
                              hipStream_t stream) {
    const float* x      = (const float*)d_in[0];
    const float* pre_w  = (const float*)d_in[1];
    const float* pre_b  = (const float*)d_in[2];
    const float* post_w = (const float*)d_in[3];
    const float* post_b = (const float*)d_in[4];
    const float* w_ry   = (const float*)d_in[5];
    const float* w_rz   = (const float*)d_in[6];
    float* out = (float*)d_out;

    const int B = in_sizes[0] / 512;  // 4096

    const int blocks = (B + 7) / 8;  // 4 waves/block, 2 elements/wave
    dqc_main_kernel<<<blocks, 256, 0, stream>>>(x, pre_w, pre_b, post_w,
                                                post_b, w_ry, w_rz, out, B);
}